// Round 13
// baseline (988.965 us; speedup 1.0000x reference)
//
#include <hip/hip_runtime.h>
#include <hip/hip_bf16.h>

#define B_    8
#define C_    64
#define N_    1024
#define HID   384
#define OUTD  128
#define L_    3
#define KNN   16
#define NHEADS 3
#define DH    128

typedef __attribute__((ext_vector_type(8))) short    s16x8;   // MFMA A/B frag: 8 bf16
typedef __attribute__((ext_vector_type(4))) float    f32x4;   // MFMA C/D frag
typedef __attribute__((ext_vector_type(8))) unsigned short u16x8;
typedef __attribute__((ext_vector_type(4))) unsigned short u16x4;

// RNE f32 -> bf16 (finite inputs)
__device__ __forceinline__ ushort f2b(float f) {
    uint x = __float_as_uint(f);
    return (ushort)((x + 0x7fff + ((x >> 16) & 1)) >> 16);
}
__device__ __forceinline__ float b2f(uint u) {
    return __uint_as_float(u << 16);
}

// ---------------------------------------------------------------- encode (+normalize +bf16 mirrors)
__global__ void k_encode(const float* __restrict__ x, const float* __restrict__ Wenc,
                         const float* __restrict__ benc, float* __restrict__ h,
                         ushort* __restrict__ hb,
                         ushort* __restrict__ nhh, ushort* __restrict__ nhl) {
    int bn = blockIdx.x;
    int b = bn >> 10;
    const float* xb = x + (long)b * C_ * N_ + (bn & 1023);
    int tid = threadIdx.x;
    __shared__ float red[128];
    float val[3];
    #pragma unroll
    for (int i = 0; i < 3; ++i) {
        int c0 = tid + i * 128;
        float acc = benc[c0];
        for (int c = 0; c < C_; ++c)
            acc += xb[c * N_] * Wenc[c * HID + c0];
        h[(long)bn * HID + c0] = acc;
        hb[(long)bn * HID + c0] = f2b(acc);
        val[i] = acc;
    }
    float ss = 0.f;
    #pragma unroll
    for (int i = 0; i < 3; ++i) ss += val[i] * val[i];
    red[tid] = ss; __syncthreads();
    for (int s = 64; s > 0; s >>= 1) { if (tid < s) red[tid] += red[tid+s]; __syncthreads(); }
    float inv = 1.0f / sqrtf(red[0]);
    #pragma unroll
    for (int i = 0; i < 3; ++i) {
        int c0 = tid + i * 128;
        float fv = val[i] * inv;
        ushort hu = f2b(fv);
        float lo = fv - b2f((uint)hu);
        nhh[(long)bn * HID + c0] = hu;
        nhl[(long)bn * HID + c0] = f2b(lo);
    }
}

// ---------------------------------------------------------------- sim = nh @ nh^T via hi/lo split MFMA
__global__ __launch_bounds__(256) void k_sim(const ushort* __restrict__ nhh,
                                             const ushort* __restrict__ nhl,
                                             float* __restrict__ sim) {
    __shared__ ushort Ah[128][40], Alo[128][40], Bh[128][40], Blo[128][40];
    int bz = blockIdx.z;
    int bm = blockIdx.y * 128, bn = blockIdx.x * 128;
    const ushort* baseh = nhh + (long)bz * N_ * HID;
    const ushort* basel = nhl + (long)bz * N_ * HID;
    int tid = threadIdx.x;
    int w = tid >> 6, l = tid & 63;
    int wm = w >> 1, wn = w & 1;
    int sr = tid >> 2, skq = (tid & 3) * 8;
    f32x4 acc[4][4] = {};
    for (int k0 = 0; k0 < HID; k0 += 32) {
        *(u16x8*)&Ah [sr][skq]      = *(const u16x8*)&baseh[(long)(bm + sr) * HID + k0 + skq];
        *(u16x8*)&Ah [sr + 64][skq] = *(const u16x8*)&baseh[(long)(bm + sr + 64) * HID + k0 + skq];
        *(u16x8*)&Alo[sr][skq]      = *(const u16x8*)&basel[(long)(bm + sr) * HID + k0 + skq];
        *(u16x8*)&Alo[sr + 64][skq] = *(const u16x8*)&basel[(long)(bm + sr + 64) * HID + k0 + skq];
        *(u16x8*)&Bh [sr][skq]      = *(const u16x8*)&baseh[(long)(bn + sr) * HID + k0 + skq];
        *(u16x8*)&Bh [sr + 64][skq] = *(const u16x8*)&baseh[(long)(bn + sr + 64) * HID + k0 + skq];
        *(u16x8*)&Blo[sr][skq]      = *(const u16x8*)&basel[(long)(bn + sr) * HID + k0 + skq];
        *(u16x8*)&Blo[sr + 64][skq] = *(const u16x8*)&basel[(long)(bn + sr + 64) * HID + k0 + skq];
        __syncthreads();
        s16x8 ah[4], al[4], bh[4], bl[4];
        #pragma unroll
        for (int mi = 0; mi < 4; ++mi) {
            ah[mi] = *(const s16x8*)&Ah [wm * 64 + mi * 16 + (l & 15)][(l >> 4) * 8];
            al[mi] = *(const s16x8*)&Alo[wm * 64 + mi * 16 + (l & 15)][(l >> 4) * 8];
        }
        #pragma unroll
        for (int ni = 0; ni < 4; ++ni) {
            bh[ni] = *(const s16x8*)&Bh [wn * 64 + ni * 16 + (l & 15)][(l >> 4) * 8];
            bl[ni] = *(const s16x8*)&Blo[wn * 64 + ni * 16 + (l & 15)][(l >> 4) * 8];
        }
        #pragma unroll
        for (int mi = 0; mi < 4; ++mi)
            #pragma unroll
            for (int ni = 0; ni < 4; ++ni) {
                acc[mi][ni] = __builtin_amdgcn_mfma_f32_16x16x32_bf16(ah[mi], bh[ni], acc[mi][ni], 0, 0, 0);
                acc[mi][ni] = __builtin_amdgcn_mfma_f32_16x16x32_bf16(ah[mi], bl[ni], acc[mi][ni], 0, 0, 0);
                acc[mi][ni] = __builtin_amdgcn_mfma_f32_16x16x32_bf16(al[mi], bh[ni], acc[mi][ni], 0, 0, 0);
            }
        __syncthreads();
    }
    float* so = sim + (long)bz * N_ * N_;
    #pragma unroll
    for (int mi = 0; mi < 4; ++mi) {
        int row0 = bm + wm * 64 + mi * 16 + (l >> 4) * 4;
        #pragma unroll
        for (int ni = 0; ni < 4; ++ni) {
            int coln = bn + wn * 64 + ni * 16 + (l & 15);
            #pragma unroll
            for (int reg = 0; reg < 4; ++reg)
                so[(long)(row0 + reg) * N_ + coln] = acc[mi][ni][reg];
        }
    }
}

// ---------------------------------------------------------------- top-k (k=16), one wave per row
__global__ __launch_bounds__(256) void k_topk(const float* __restrict__ sim, int* __restrict__ knn) {
    int tid = threadIdx.x;
    int wave = tid >> 6, ll = tid & 63;
    int bn = blockIdx.x * 4 + wave;
    int b = bn >> 10, n = bn & 1023;
    const float* row = sim + (long)b * N_ * N_ + (long)n * N_;
    float v[16];
    #pragma unroll
    for (int j = 0; j < 16; ++j) {
        int m = ll + j * 64;
        v[j] = row[m] - (m == n ? 2.0f : 0.0f);
    }
    int* kout = knn + (long)bn * KNN;
    for (int it = 0; it < KNN; ++it) {
        float bv = v[0]; int bi = ll;
        #pragma unroll
        for (int j = 1; j < 16; ++j)
            if (v[j] > bv) { bv = v[j]; bi = ll + j * 64; }
        #pragma unroll
        for (int mask = 1; mask < 64; mask <<= 1) {
            float ov = __shfl_xor(bv, mask);
            int   oi = __shfl_xor(bi, mask);
            if (ov > bv || (ov == bv && oi < bi)) { bv = ov; bi = oi; }
        }
        if (ll == 0) kout[it] = bi;
        if ((bi & 63) == ll) v[bi >> 6] = -1e30f;
    }
}

// ---------------------------------------------------------------- weight cast+transpose
// slots: layer l -> [gcn|q|k|v] at l*4+{0,1,2,3} (contiguous per layer) ; o -> 12+l
__global__ void k_cast15(const float* __restrict__ g, const float* __restrict__ q,
                         const float* __restrict__ k, const float* __restrict__ v,
                         const float* __restrict__ o, ushort* __restrict__ out) {
    int z = blockIdx.z; int type = z / 3, l = z % 3;
    const float* in = (type == 0 ? g : type == 1 ? q : type == 2 ? k : type == 3 ? v : o)
                      + (long)l * HID * HID;
    int slot = (type == 4) ? 12 + l : l * 4 + type;
    ushort* op = out + (long)slot * HID * HID;
    __shared__ float t[32][33];
    int c0 = blockIdx.x * 32, r0 = blockIdx.y * 32;
    int tid = threadIdx.x; int i = tid & 31, j4 = tid >> 5;
    #pragma unroll
    for (int rr = 0; rr < 4; ++rr) {
        int r = j4 * 4 + rr;
        t[r][i] = in[(long)(r0 + r) * HID + c0 + i];
    }
    __syncthreads();
    #pragma unroll
    for (int rr = 0; rr < 4; ++rr) {
        int c = j4 * 4 + rr;
        op[(long)(c0 + c) * HID + r0 + i] = f2b(t[i][c]);
    }
}

__global__ void k_castT(const float* __restrict__ in_, ushort* __restrict__ out_,
                        int R, int C) {
    long mz = (long)blockIdx.z * R * C;
    const float* in = in_ + mz;
    ushort* op = out_ + mz;
    __shared__ float t[32][33];
    int c0 = blockIdx.x * 32, r0 = blockIdx.y * 32;
    int tid = threadIdx.x; int i = tid & 31, j4 = tid >> 5;
    #pragma unroll
    for (int rr = 0; rr < 4; ++rr) {
        int r = j4 * 4 + rr;
        t[r][i] = in[(long)(r0 + r) * C + c0 + i];
    }
    __syncthreads();
    #pragma unroll
    for (int rr = 0; rr < 4; ++rr) {
        int c = j4 * 4 + rr;
        op[(long)(c0 + c) * R + r0 + i] = f2b(t[i][c]);
    }
}

// concat biases: out[l][0:384)=gcn_b, [384:768)=bq, [768:1152)=bk, [1152:1536)=bv
__global__ void k_biasgqkv(const float* __restrict__ gb, const float* __restrict__ bq,
                           const float* __restrict__ bk, const float* __restrict__ bv,
                           float* __restrict__ out) {
    int l = blockIdx.x, t = threadIdx.x;
    out[l * 1536 + t]        = gb[l * HID + t];
    out[l * 1536 + 384 + t]  = bq[l * HID + t];
    out[l * 1536 + 768 + t]  = bk[l * HID + t];
    out[l * 1536 + 1152 + t] = bv[l * HID + t];
}

// ---------------------------------------------------------------- MFMA GEMM v2 (128x128 tile)
// OUTMODE: 0 = f32 [M][N], 1 = bf16 [M][N],
//          5 = fused gcn|q|k|v: coln<384 -> f32 CoutF [M][384]; 384..1152 -> bf16 Cout rows
//              stride 768 at coln-384; >=1152 -> transposed CoutT [384][ldcT] at coln-1152
template<int OUTMODE, bool RELU>
__global__ __launch_bounds__(256) void k_mgemm(
        const ushort* __restrict__ A, const ushort* __restrict__ Wt,
        const float* __restrict__ bias, const float* __restrict__ resid,
        void* __restrict__ Cout, void* __restrict__ CoutT, void* __restrict__ CoutF,
        int M, int N, int K, long ldcT) {
    __shared__ ushort Al[128][40];   // row stride 80B
    __shared__ ushort Bl[128][40];
    int bm = blockIdx.y * 128, bnn = blockIdx.x * 128;
    int tid = threadIdx.x;
    int w = tid >> 6, l = tid & 63;
    int wm = w >> 1, wn = w & 1;
    int sr = tid >> 2, skq = (tid & 3) * 8;
    f32x4 acc[4][4] = {};
    for (int k0 = 0; k0 < K; k0 += 32) {
        *(u16x8*)&Al[sr][skq]      = *(const u16x8*)&A [(long)(bm + sr) * K + k0 + skq];
        *(u16x8*)&Al[sr + 64][skq] = *(const u16x8*)&A [(long)(bm + sr + 64) * K + k0 + skq];
        *(u16x8*)&Bl[sr][skq]      = *(const u16x8*)&Wt[(long)(bnn + sr) * K + k0 + skq];
        *(u16x8*)&Bl[sr + 64][skq] = *(const u16x8*)&Wt[(long)(bnn + sr + 64) * K + k0 + skq];
        __syncthreads();
        s16x8 af[4], bf[4];
        #pragma unroll
        for (int mi = 0; mi < 4; ++mi)
            af[mi] = *(const s16x8*)&Al[wm * 64 + mi * 16 + (l & 15)][(l >> 4) * 8];
        #pragma unroll
        for (int ni = 0; ni < 4; ++ni)
            bf[ni] = *(const s16x8*)&Bl[wn * 64 + ni * 16 + (l & 15)][(l >> 4) * 8];
        #pragma unroll
        for (int mi = 0; mi < 4; ++mi)
            #pragma unroll
            for (int ni = 0; ni < 4; ++ni)
                acc[mi][ni] = __builtin_amdgcn_mfma_f32_16x16x32_bf16(af[mi], bf[ni], acc[mi][ni], 0, 0, 0);
        __syncthreads();
    }
    #pragma unroll
    for (int mi = 0; mi < 4; ++mi) {
        int row0 = bm + wm * 64 + mi * 16 + (l >> 4) * 4;
        #pragma unroll
        for (int ni = 0; ni < 4; ++ni) {
            int coln = bnn + wn * 64 + ni * 16 + (l & 15);
            float bv = bias[coln];
            if (OUTMODE == 5) {
                if (coln < 384) {
                    #pragma unroll
                    for (int reg = 0; reg < 4; ++reg)
                        ((float*)CoutF)[(long)(row0 + reg) * HID + coln] = acc[mi][ni][reg] + bv;
                } else if (coln < 1152) {
                    #pragma unroll
                    for (int reg = 0; reg < 4; ++reg)
                        ((ushort*)Cout)[(long)(row0 + reg) * 768 + (coln - 384)] = f2b(acc[mi][ni][reg] + bv);
                } else {
                    u16x4 pk;
                    #pragma unroll
                    for (int reg = 0; reg < 4; ++reg)
                        pk[reg] = f2b(acc[mi][ni][reg] + bv);
                    *(u16x4*)((ushort*)CoutT + (long)(coln - 1152) * ldcT + row0) = pk;
                }
            } else {
                #pragma unroll
                for (int reg = 0; reg < 4; ++reg) {
                    int rowg = row0 + reg;
                    float v = acc[mi][ni][reg] + bv;
                    if (resid) v += resid[(long)rowg * N + coln];
                    if (RELU)  v = fmaxf(v, 0.f);
                    if (OUTMODE == 0) ((float*)Cout)[(long)rowg * N + coln] = v;
                    else              ((ushort*)Cout)[(long)rowg * N + coln] = f2b(v);
                }
            }
        }
    }
}

// ---------------------------------------------------------------- GCN gather + residual + LN (f32)
__global__ void k_gcn_ln(const float* __restrict__ h, const float* __restrict__ xw,
                         const int* __restrict__ knn,
                         const float* __restrict__ lns, const float* __restrict__ lnb,
                         float* __restrict__ hlocal) {
    int bn = blockIdx.x; int b = bn >> 10;
    __shared__ int nb[KNN];
    __shared__ float red[128];
    int tid = threadIdx.x;
    if (tid < KNN) nb[tid] = knn[(long)bn * KNN + tid];
    __syncthreads();
    float val[3]; float sum = 0.f, ssq = 0.f;
    #pragma unroll
    for (int i = 0; i < 3; ++i) {
        int c = tid + i * 128;
        float acc = xw[(long)bn * HID + c];
        #pragma unroll
        for (int j = 0; j < KNN; ++j)
            acc += xw[((long)(b << 10) + nb[j]) * HID + c];
        float v = h[(long)bn * HID + c] + acc * (1.0f / 17.0f);
        val[i] = v; sum += v; ssq += v * v;
    }
    red[tid] = sum; __syncthreads();
    for (int s = 64; s > 0; s >>= 1) { if (tid < s) red[tid] += red[tid+s]; __syncthreads(); }
    sum = red[0]; __syncthreads();
    red[tid] = ssq; __syncthreads();
    for (int s = 64; s > 0; s >>= 1) { if (tid < s) red[tid] += red[tid+s]; __syncthreads(); }
    ssq = red[0];
    float mu = sum / HID;
    float var = ssq / HID - mu * mu;
    float inv = rsqrtf(var + 1e-5f);
    #pragma unroll
    for (int i = 0; i < 3; ++i) {
        int c = tid + i * 128;
        hlocal[(long)bn * HID + c] = (val[i] - mu) * inv * lns[c] + lnb[c];
    }
}

// ---------------------------------------------------------------- (a[+badd]) -> LN -> (+post), + bf16 mirror
__global__ void k_addln(const float* __restrict__ a, const float* __restrict__ badd,
                        const float* __restrict__ post,
                        const float* __restrict__ lns, const float* __restrict__ lnb,
                        float* __restrict__ outp, ushort* __restrict__ bfout) {
    int bn = blockIdx.x;
    __shared__ float red[128];
    int tid = threadIdx.x;
    float val[3]; float sum = 0.f, ssq = 0.f;
    #pragma unroll
    for (int i = 0; i < 3; ++i) {
        int c = tid + i * 128;
        float v = a[(long)bn * HID + c];
        if (badd) v += badd[(long)bn * HID + c];
        val[i] = v; sum += v; ssq += v * v;
    }
    red[tid] = sum; __syncthreads();
    for (int s = 64; s > 0; s >>= 1) { if (tid < s) red[tid] += red[tid+s]; __syncthreads(); }
    sum = red[0]; __syncthreads();
    red[tid] = ssq; __syncthreads();
    for (int s = 64; s > 0; s >>= 1) { if (tid < s) red[tid] += red[tid+s]; __syncthreads(); }
    ssq = red[0];
    float mu = sum / HID;
    float var = ssq / HID - mu * mu;
    float inv = rsqrtf(var + 1e-5f);
    #pragma unroll
    for (int i = 0; i < 3; ++i) {
        int c = tid + i * 128;
        float o = (val[i] - mu) * inv * lns[c] + lnb[c];
        if (post) o += post[(long)bn * HID + c];
        outp[(long)bn * HID + c] = o;
        if (bfout) bfout[(long)bn * HID + c] = f2b(o);
    }
}

// ---------------------------------------------------------------- MFMA attention (staged, padded strides)
// LDS-staged K/V tiles (coalesced global loads), strides 140/76 elems (bank stride
// 6 mod 32 -> 16 row-lanes hit 16 distinct banks on ds_read_b128).
__global__ __launch_bounds__(256) void k_attn(const ushort* __restrict__ qk,
                                              const ushort* __restrict__ vt,
                                              ushort* __restrict__ o) {
    int b = blockIdx.z, hh = blockIdx.y, r0 = blockIdx.x * 16;
    __shared__ ushort sc[16][1032];     // bf16 scores/probs; stride 2064B
    __shared__ ushort kvt[9728];        // union: Kt[64][140] | VtT[128][76]
    __shared__ float rowinv[16];
    int tid = threadIdx.x;
    int w = tid >> 6, l = tid & 63;
    s16x8 aq[4];
    const ushort* qrow = qk + ((long)(b * N_) + r0 + (l & 15)) * 768 + hh * DH + (l >> 4) * 8;
    #pragma unroll
    for (int ks = 0; ks < 4; ++ks) aq[ks] = *(const s16x8*)(qrow + ks * 32);
    const float scale = 0.08838834764831845f;   // 1/sqrt(128)
    // ---------- S = Q K^T
    for (int m0 = 0; m0 < N_; m0 += 64) {
        {   // stage K tile [64 keys][128 dh] -> Kt[key][140]
            int key = tid >> 2, seg = tid & 3;
            const ushort* src = qk + ((long)(b * N_) + m0 + key) * 768 + 384 + hh * DH + seg * 32;
            ushort* dst = &kvt[key * 140 + seg * 32];
            #pragma unroll
            for (int i = 0; i < 4; ++i)
                *(u16x8*)(dst + i * 8) = *(const u16x8*)(src + i * 8);
        }
        __syncthreads();
        f32x4 acc = {0.f, 0.f, 0.f, 0.f};
        #pragma unroll
        for (int ks = 0; ks < 4; ++ks) {
            s16x8 bk = *(const s16x8*)&kvt[(w * 16 + (l & 15)) * 140 + ks * 32 + (l >> 4) * 8];
            acc = __builtin_amdgcn_mfma_f32_16x16x32_bf16(aq[ks], bk, acc, 0, 0, 0);
        }
        int key = m0 + w * 16 + (l & 15);
        #pragma unroll
        for (int reg = 0; reg < 4; ++reg)
            sc[(l >> 4) * 4 + reg][key] = f2b(acc[reg] * scale);
        __syncthreads();
    }
    // ---------- softmax (32-lane group per row, registers + shfl)
    {
        int g = tid >> 5, l2 = tid & 31;
        #pragma unroll
        for (int rr = 0; rr < 2; ++rr) {
            int row = g + rr * 8;
            float v[32];
            #pragma unroll
            for (int i = 0; i < 16; ++i) {
                uint u = *(const uint*)&sc[row][l2 * 2 + i * 64];
                v[2*i]   = b2f(u & 0xffffu);
                v[2*i+1] = b2f(u >> 16);
            }
            float mx = v[0];
            #pragma unroll
            for (int i = 1; i < 32; ++i) mx = fmaxf(mx, v[i]);
            #pragma unroll
            for (int m = 16; m >= 1; m >>= 1) mx = fmaxf(mx, __shfl_xor(mx, m));
            float sm = 0.f;
            #pragma unroll
            for (int i = 0; i < 16; ++i) {
                float e0 = __expf(v[2*i]   - mx);
                float e1 = __expf(v[2*i+1] - mx);
                sm += e0 + e1;
                *(uint*)&sc[row][l2 * 2 + i * 64] = (uint)f2b(e0) | ((uint)f2b(e1) << 16);
            }
            #pragma unroll
            for (int m = 16; m >= 1; m >>= 1) sm += __shfl_xor(sm, m);
            if (l2 == 0) rowinv[row] = 1.0f / sm;
        }
    }
    __syncthreads();
    // ---------- O = P V
    f32x4 zero = {0.f, 0.f, 0.f, 0.f};
    f32x4 oacc[2] = {zero, zero};
    for (int m0 = 0; m0 < N_; m0 += 64) {
        {   // stage V^T tile [128 dims][64 keys] -> VtT[dim][76]
            int dim = tid >> 1, half = tid & 1;
            const ushort* src = vt + ((long)(hh * DH + dim)) * (B_ * N_) + b * N_ + m0 + half * 32;
            ushort* dst = &kvt[dim * 76 + half * 32];
            #pragma unroll
            for (int i = 0; i < 4; ++i)
                *(u16x8*)(dst + i * 8) = *(const u16x8*)(src + i * 8);
        }
        __syncthreads();
        #pragma unroll
        for (int ks = 0; ks < 2; ++ks) {
            s16x8 pf = *(const s16x8*)&sc[l & 15][m0 + ks * 32 + (l >> 4) * 8];
            #pragma unroll
            for (int d = 0; d < 2; ++d) {
                s16x8 vf = *(const s16x8*)&kvt[((w * 2 + d) * 16 + (l & 15)) * 76 + ks * 32 + (l >> 4) * 8];
                oacc[d] = __builtin_amdgcn_mfma_f32_16x16x32_bf16(pf, vf, oacc[d], 0, 0, 0);
            }
        }
        __syncthreads();
    }
    #pragma unroll
    for (int d = 0; d < 2; ++d) {
        int dim = (w * 2 + d) * 16 + (l & 15);
        #pragma unroll
        for (int reg = 0; reg < 4; ++reg) {
            int row = (l >> 4) * 4 + reg;
            o[((long)(b * N_) + r0 + row) * HID + hh * DH + dim] = f2b(oacc[d][reg] * rowinv[row]);
        }
    }
}

// ---------------------------------------------------------------- mean pool, two-stage
__global__ __launch_bounds__(384) void k_pool1(const float* __restrict__ h,
                                               float* __restrict__ partial) {
    int s = blockIdx.x, b = blockIdx.y;
    int c = threadIdx.x;
    const float* hp = h + ((long)(b * N_) + s * 32) * HID + c;
    float acc = 0.f;
    #pragma unroll
    for (int n = 0; n < 32; ++n) acc += hp[(long)n * HID];
    partial[((long)(b * 32) + s) * HID + c] = acc;
}
__global__ __launch_bounds__(384) void k_pool2(const float* __restrict__ partial,
                                               float* __restrict__ pooled) {
    int b = blockIdx.x;
    int c = threadIdx.x;
    const float* pp = partial + (long)(b * 32) * HID + c;
    float acc = 0.f;
    #pragma unroll
    for (int s = 0; s < 32; ++s) acc += pp[(long)s * HID];
    pooled[b * HID + c] = acc * (1.0f / N_);
}

// ---------------------------------------------------------------- head (f32)
__global__ void k_head(const float* __restrict__ pooled,
                       const float* __restrict__ w1, const float* __restrict__ b1,
                       const float* __restrict__ w2, const float* __restrict__ b2,
                       float* __restrict__ out) {
    int b = blockIdx.x; int tid = threadIdx.x;   // 384 threads
    __shared__ float z[HID];
    float acc = b1[tid];
    for (int c = 0; c < HID; ++c) acc += pooled[b * HID + c] * w1[c * HID + tid];
    z[tid] = fmaxf(acc, 0.f);
    __syncthreads();
    if (tid < OUTD) {
        float a2 = b2[tid];
        for (int j = 0; j < HID; ++j) a2 += z[j] * w2[j * OUTD + tid];
        out[b * OUTD + tid] = a2;
    }
}

// ================================================================ launch
extern "C" void kernel_launch(void* const* d_in, const int* in_sizes, int n_in,
                              void* d_out, int out_size, void* d_ws, size_t ws_size,
                              hipStream_t stream) {
    const float* x       = (const float*)d_in[0];
    const float* W_enc   = (const float*)d_in[1];
    const float* b_enc   = (const float*)d_in[2];
    const float* gcn_W   = (const float*)d_in[3];
    const float* gcn_b   = (const float*)d_in[4];
    const float* Wq      = (const float*)d_in[5];
    const float* bq      = (const float*)d_in[6];
    const float* Wk      = (const float*)d_in[7];
    const float* bk      = (const float*)d_in[8];
    const float* Wv      = (const float*)d_in[9];
    const float* bv      = (const float*)d_in[10];
    const float* Wo      = (const float*)d_in[11];
    const float* bo      = (const float*)d_in[12];
    const float* ln_s    = (const float*)d_in[13];
    const float* ln_b    = (const float*)d_in[14];
    const float* mlp_W1  = (const float*)d_in[15];
    const float* mlp_b1  = (const float*)d_in[16];
    const float* mlp_W2  = (const float*)d_in[17];
    const float* mlp_b2  = (const float*)d_in[18];
    const float* lin1_W  = (const float*)d_in[19];
    const float* lin1_b  = (const float*)d_in[20];
    const float* lin2_W  = (const float*)d_in[21];
    const float* lin2_b  = (const float*)d_in[22];

    const long S = (long)B_ * N_ * HID;            // 3,145,728
    char* base = (char*)d_ws;
    float* h      = (float*)(base);
    float* tmp1   = (float*)(base + (size_t)S * 4);       // xw / attn-out(bf16) / u / pool-partial / nhh+nhl
    float* hlocal = (float*)(base + (size_t)S * 8);
    float* outb   = (float*)(base + (size_t)S * 12);
    char*  tzone  = base + (size_t)S * 16;                // 8S-byte multi-use region
    float* proj   = (float*)(base + (size_t)S * 24);
    float*  sim = (float*)tzone;                          // phase-1 (spills into proj)
    ushort* qkbf = (ushort*)tzone;                        // [0,4S): fused q|k rows stride 768
    ushort* vbT  = (ushort*)(tzone + (size_t)S * 4);      // [4S,6S)
    ushort* outb_bf = (ushort*)(tzone + (size_t)S * 6);   // [6S,8S)
    ushort* tb  = (ushort*)tzone;                         // [0,4S) after attn (mlp hidden)
    ushort* nhh = (ushort*)(base + (size_t)S * 4);        // phase-1 overlay of tmp1
    ushort* nhl = (ushort*)(base + (size_t)S * 6);
    int*    knn    = (int*)(base + (size_t)S * 28);
    float*  pooled = (float*)(base + (size_t)S * 28 + 524288);
    ushort* wts    = (ushort*)(base + (size_t)S * 28 + 524288 + 16384);
    const long SQ = (long)HID * HID;
    ushort* w1T = wts + 15 * SQ;
    ushort* w2T = w1T + 3 * (long)HID * 2 * HID;
    ushort* hb  = (ushort*)(base + (size_t)S * 28 + 524288 + 16384 + 7962624);
    float* gqkvb = (float*)(base + (size_t)S * 28 + 524288 + 16384 + 7962624 + (size_t)S * 2);
    float* partial = tmp1;
    ushort* obf = (ushort*)tmp1;                          // attn bf16 out (tmp1 dead)

    // ---- weight cast+transpose (bf16 [N][K]) + bias concat
    k_cast15<<<dim3(12, 12, 15), 256, 0, stream>>>(gcn_W, Wq, Wk, Wv, Wo, wts);
    k_castT<<<dim3(24, 12, 3), 256, 0, stream>>>(mlp_W1, w1T, HID, 2 * HID);
    k_castT<<<dim3(12, 24, 3), 256, 0, stream>>>(mlp_W2, w2T, 2 * HID, HID);
    k_biasgqkv<<<3, 384, 0, stream>>>(gcn_b, bq, bk, bv, gqkvb);

    // ---- encode(+normalize+mirrors) + sim (hi/lo MFMA) + topk
    k_encode<<<B_ * N_, 128, 0, stream>>>(x, W_enc, b_enc, h, hb, nhh, nhl);
    k_sim<<<dim3(8, 8, 8), 256, 0, stream>>>(nhh, nhl, sim);
    k_topk<<<B_ * N_ / 4, 256, 0, stream>>>(sim, knn);

    const int M = B_ * N_;   // 8192
    for (int l = 0; l < L_; ++l) {
        const ushort* gqkvW = wts + (long)(l * 4) * SQ;       // [gcn|q|k|v] rows [1536][384]
        const ushort* woT   = wts + (long)(12 + l) * SQ;
        const ushort* w1Tl = w1T + (long)l * HID * 2 * HID;
        const ushort* w2Tl = w2T + (long)l * HID * 2 * HID;
        const float* bol = bo + (long)l * HID;
        const float* b1l = mlp_b1 + (long)l * 2 * HID;
        const float* b2l = mlp_b2 + (long)l * HID;
        const float* ls0 = ln_s + (long)(l * 3 + 0) * HID; const float* lb0 = ln_b + (long)(l * 3 + 0) * HID;
        const float* ls1 = ln_s + (long)(l * 3 + 1) * HID; const float* lb1 = ln_b + (long)(l * 3 + 1) * HID;
        const float* ls2 = ln_s + (long)(l * 3 + 2) * HID; const float* lb2 = ln_b + (long)(l * 3 + 2) * HID;

        // fused xw|q|k|v: one GEMM, N=1536 (xw f32 -> tmp1; q/k bf16 rows 768; v transposed)
        k_mgemm<5, false><<<dim3(1536 / 128, M / 128), 256, 0, stream>>>(
            hb, gqkvW, gqkvb + l * 1536, nullptr, qkbf, vbT, tmp1, M, 1536, HID, (long)M);
        k_gcn_ln<<<B_ * N_, 128, 0, stream>>>(h, tmp1, knn, ls0, lb0, hlocal);
        // attention -> obf (bf16)
        k_attn<<<dim3(N_ / 16, NHEADS, B_), 256, 0, stream>>>(qkbf, vbT, obf);
        // proj = o @ Wo + bo (f32)
        k_mgemm<0, false><<<dim3(HID / 128, M / 128), 256, 0, stream>>>(
            obf, woT, bol, nullptr, proj, nullptr, nullptr, M, HID, HID, 0);
        // out = hlocal + LN(h + proj) -> outb (+bf16 mirror)
        k_addln<<<B_ * N_, 128, 0, stream>>>(h, proj, hlocal, ls1, lb1, outb, outb_bf);
        // t = relu(out @ W1 + b1) -> bf16 tb
        k_mgemm<1, true><<<dim3(2 * HID / 128, M / 128), 256, 0, stream>>>(
            outb_bf, w1Tl, b1l, nullptr, tb, nullptr, nullptr, M, 2 * HID, HID, 0);
        // u = out + t @ W2 + b2 -> tmp1 (f32)
        k_mgemm<0, false><<<dim3(HID / 128, M / 128), 256, 0, stream>>>(
            tb, w2Tl, b2l, outb, tmp1, nullptr, nullptr, M, HID, 2 * HID, 0);
        // h = LN(u) (+hb mirror)
        k_addln<<<B_ * N_, 128, 0, stream>>>(tmp1, nullptr, nullptr, ls2, lb2, h, hb);
    }

    k_pool1<<<dim3(32, B_), 384, 0, stream>>>(h, partial);
    k_pool2<<<B_, 384, 0, stream>>>(partial, pooled);
    k_head<<<B_, HID, 0, stream>>>(pooled, lin1_W, lin1_b, lin2_W, lin2_b,
                                   (float*)d_out);
}

// Round 14
// 833.790 us; speedup vs baseline: 1.1861x; 1.1861x over previous
//
#include <hip/hip_runtime.h>
#include <hip/hip_bf16.h>

#define B_    8
#define C_    64
#define N_    1024
#define HID   384
#define OUTD  128
#define L_    3
#define KNN   16
#define NHEADS 3
#define DH    128

typedef __attribute__((ext_vector_type(8))) short    s16x8;   // MFMA A/B frag: 8 bf16
typedef __attribute__((ext_vector_type(4))) float    f32x4;   // MFMA C/D frag
typedef __attribute__((ext_vector_type(8))) unsigned short u16x8;
typedef __attribute__((ext_vector_type(4))) unsigned short u16x4;

// RNE f32 -> bf16 (finite inputs)
__device__ __forceinline__ ushort f2b(float f) {
    uint x = __float_as_uint(f);
    return (ushort)((x + 0x7fff + ((x >> 16) & 1)) >> 16);
}
__device__ __forceinline__ float b2f(uint u) {
    return __uint_as_float(u << 16);
}

// ---------------------------------------------------------------- encode (+normalize +bf16 mirrors)
__global__ void k_encode(const float* __restrict__ x, const float* __restrict__ Wenc,
                         const float* __restrict__ benc, float* __restrict__ h,
                         ushort* __restrict__ hb,
                         ushort* __restrict__ nhh, ushort* __restrict__ nhl) {
    int bn = blockIdx.x;
    int b = bn >> 10;
    const float* xb = x + (long)b * C_ * N_ + (bn & 1023);
    int tid = threadIdx.x;
    __shared__ float red[128];
    float val[3];
    #pragma unroll
    for (int i = 0; i < 3; ++i) {
        int c0 = tid + i * 128;
        float acc = benc[c0];
        for (int c = 0; c < C_; ++c)
            acc += xb[c * N_] * Wenc[c * HID + c0];
        h[(long)bn * HID + c0] = acc;
        hb[(long)bn * HID + c0] = f2b(acc);
        val[i] = acc;
    }
    float ss = 0.f;
    #pragma unroll
    for (int i = 0; i < 3; ++i) ss += val[i] * val[i];
    red[tid] = ss; __syncthreads();
    for (int s = 64; s > 0; s >>= 1) { if (tid < s) red[tid] += red[tid+s]; __syncthreads(); }
    float inv = 1.0f / sqrtf(red[0]);
    #pragma unroll
    for (int i = 0; i < 3; ++i) {
        int c0 = tid + i * 128;
        float fv = val[i] * inv;
        ushort hu = f2b(fv);
        float lo = fv - b2f((uint)hu);
        nhh[(long)bn * HID + c0] = hu;
        nhl[(long)bn * HID + c0] = f2b(lo);
    }
}

// ---------------------------------------------------------------- sim = nh @ nh^T via hi/lo split MFMA
__global__ __launch_bounds__(256) void k_sim(const ushort* __restrict__ nhh,
                                             const ushort* __restrict__ nhl,
                                             float* __restrict__ sim) {
    __shared__ ushort Ah[128][40], Alo[128][40], Bh[128][40], Blo[128][40];
    int bz = blockIdx.z;
    int bm = blockIdx.y * 128, bn = blockIdx.x * 128;
    const ushort* baseh = nhh + (long)bz * N_ * HID;
    const ushort* basel = nhl + (long)bz * N_ * HID;
    int tid = threadIdx.x;
    int w = tid >> 6, l = tid & 63;
    int wm = w >> 1, wn = w & 1;
    int sr = tid >> 2, skq = (tid & 3) * 8;
    f32x4 acc[4][4] = {};
    for (int k0 = 0; k0 < HID; k0 += 32) {
        *(u16x8*)&Ah [sr][skq]      = *(const u16x8*)&baseh[(long)(bm + sr) * HID + k0 + skq];
        *(u16x8*)&Ah [sr + 64][skq] = *(const u16x8*)&baseh[(long)(bm + sr + 64) * HID + k0 + skq];
        *(u16x8*)&Alo[sr][skq]      = *(const u16x8*)&basel[(long)(bm + sr) * HID + k0 + skq];
        *(u16x8*)&Alo[sr + 64][skq] = *(const u16x8*)&basel[(long)(bm + sr + 64) * HID + k0 + skq];
        *(u16x8*)&Bh [sr][skq]      = *(const u16x8*)&baseh[(long)(bn + sr) * HID + k0 + skq];
        *(u16x8*)&Bh [sr + 64][skq] = *(const u16x8*)&baseh[(long)(bn + sr + 64) * HID + k0 + skq];
        *(u16x8*)&Blo[sr][skq]      = *(const u16x8*)&basel[(long)(bn + sr) * HID + k0 + skq];
        *(u16x8*)&Blo[sr + 64][skq] = *(const u16x8*)&basel[(long)(bn + sr + 64) * HID + k0 + skq];
        __syncthreads();
        s16x8 ah[4], al[4], bh[4], bl[4];
        #pragma unroll
        for (int mi = 0; mi < 4; ++mi) {
            ah[mi] = *(const s16x8*)&Ah [wm * 64 + mi * 16 + (l & 15)][(l >> 4) * 8];
            al[mi] = *(const s16x8*)&Alo[wm * 64 + mi * 16 + (l & 15)][(l >> 4) * 8];
        }
        #pragma unroll
        for (int ni = 0; ni < 4; ++ni) {
            bh[ni] = *(const s16x8*)&Bh [wn * 64 + ni * 16 + (l & 15)][(l >> 4) * 8];
            bl[ni] = *(const s16x8*)&Blo[wn * 64 + ni * 16 + (l & 15)][(l >> 4) * 8];
        }
        #pragma unroll
        for (int mi = 0; mi < 4; ++mi)
            #pragma unroll
            for (int ni = 0; ni < 4; ++ni) {
                acc[mi][ni] = __builtin_amdgcn_mfma_f32_16x16x32_bf16(ah[mi], bh[ni], acc[mi][ni], 0, 0, 0);
                acc[mi][ni] = __builtin_amdgcn_mfma_f32_16x16x32_bf16(ah[mi], bl[ni], acc[mi][ni], 0, 0, 0);
                acc[mi][ni] = __builtin_amdgcn_mfma_f32_16x16x32_bf16(al[mi], bh[ni], acc[mi][ni], 0, 0, 0);
            }
        __syncthreads();
    }
    float* so = sim + (long)bz * N_ * N_;
    #pragma unroll
    for (int mi = 0; mi < 4; ++mi) {
        int row0 = bm + wm * 64 + mi * 16 + (l >> 4) * 4;
        #pragma unroll
        for (int ni = 0; ni < 4; ++ni) {
            int coln = bn + wn * 64 + ni * 16 + (l & 15);
            #pragma unroll
            for (int reg = 0; reg < 4; ++reg)
                so[(long)(row0 + reg) * N_ + coln] = acc[mi][ni][reg];
        }
    }
}

// ---------------------------------------------------------------- top-k (k=16), one wave per row
__global__ __launch_bounds__(256) void k_topk(const float* __restrict__ sim, int* __restrict__ knn) {
    int tid = threadIdx.x;
    int wave = tid >> 6, ll = tid & 63;
    int bn = blockIdx.x * 4 + wave;
    int b = bn >> 10, n = bn & 1023;
    const float* row = sim + (long)b * N_ * N_ + (long)n * N_;
    float v[16];
    #pragma unroll
    for (int j = 0; j < 16; ++j) {
        int m = ll + j * 64;
        v[j] = row[m] - (m == n ? 2.0f : 0.0f);
    }
    int* kout = knn + (long)bn * KNN;
    for (int it = 0; it < KNN; ++it) {
        float bv = v[0]; int bi = ll;
        #pragma unroll
        for (int j = 1; j < 16; ++j)
            if (v[j] > bv) { bv = v[j]; bi = ll + j * 64; }
        #pragma unroll
        for (int mask = 1; mask < 64; mask <<= 1) {
            float ov = __shfl_xor(bv, mask);
            int   oi = __shfl_xor(bi, mask);
            if (ov > bv || (ov == bv && oi < bi)) { bv = ov; bi = oi; }
        }
        if (ll == 0) kout[it] = bi;
        if ((bi & 63) == ll) v[bi >> 6] = -1e30f;
    }
}

// ---------------------------------------------------------------- weight cast+transpose
// slots: layer l -> [gcn|q|k|v] at l*4+{0,1,2,3} (contiguous per layer) ; o -> 12+l
__global__ void k_cast15(const float* __restrict__ g, const float* __restrict__ q,
                         const float* __restrict__ k, const float* __restrict__ v,
                         const float* __restrict__ o, ushort* __restrict__ out) {
    int z = blockIdx.z; int type = z / 3, l = z % 3;
    const float* in = (type == 0 ? g : type == 1 ? q : type == 2 ? k : type == 3 ? v : o)
                      + (long)l * HID * HID;
    int slot = (type == 4) ? 12 + l : l * 4 + type;
    ushort* op = out + (long)slot * HID * HID;
    __shared__ float t[32][33];
    int c0 = blockIdx.x * 32, r0 = blockIdx.y * 32;
    int tid = threadIdx.x; int i = tid & 31, j4 = tid >> 5;
    #pragma unroll
    for (int rr = 0; rr < 4; ++rr) {
        int r = j4 * 4 + rr;
        t[r][i] = in[(long)(r0 + r) * HID + c0 + i];
    }
    __syncthreads();
    #pragma unroll
    for (int rr = 0; rr < 4; ++rr) {
        int c = j4 * 4 + rr;
        op[(long)(c0 + c) * HID + r0 + i] = f2b(t[i][c]);
    }
}

__global__ void k_castT(const float* __restrict__ in_, ushort* __restrict__ out_,
                        int R, int C) {
    long mz = (long)blockIdx.z * R * C;
    const float* in = in_ + mz;
    ushort* op = out_ + mz;
    __shared__ float t[32][33];
    int c0 = blockIdx.x * 32, r0 = blockIdx.y * 32;
    int tid = threadIdx.x; int i = tid & 31, j4 = tid >> 5;
    #pragma unroll
    for (int rr = 0; rr < 4; ++rr) {
        int r = j4 * 4 + rr;
        t[r][i] = in[(long)(r0 + r) * C + c0 + i];
    }
    __syncthreads();
    #pragma unroll
    for (int rr = 0; rr < 4; ++rr) {
        int c = j4 * 4 + rr;
        op[(long)(c0 + c) * R + r0 + i] = f2b(t[i][c]);
    }
}

// concat biases: out[l][0:384)=gcn_b, [384:768)=bq, [768:1152)=bk, [1152:1536)=bv
__global__ void k_biasgqkv(const float* __restrict__ gb, const float* __restrict__ bq,
                           const float* __restrict__ bk, const float* __restrict__ bv,
                           float* __restrict__ out) {
    int l = blockIdx.x, t = threadIdx.x;
    out[l * 1536 + t]        = gb[l * HID + t];
    out[l * 1536 + 384 + t]  = bq[l * HID + t];
    out[l * 1536 + 768 + t]  = bk[l * HID + t];
    out[l * 1536 + 1152 + t] = bv[l * HID + t];
}

// ---------------------------------------------------------------- MFMA GEMM v2 (128x128 tile)
// OUTMODE: 0 = f32 [M][N], 1 = bf16 [M][N],
//          5 = fused gcn|q|k|v: coln<384 -> f32 CoutF [M][384]; 384..1152 -> bf16 Cout rows
//              stride 768 at coln-384; >=1152 -> transposed CoutT [384][ldcT] at coln-1152
template<int OUTMODE, bool RELU>
__global__ __launch_bounds__(256) void k_mgemm(
        const ushort* __restrict__ A, const ushort* __restrict__ Wt,
        const float* __restrict__ bias, const float* __restrict__ resid,
        void* __restrict__ Cout, void* __restrict__ CoutT, void* __restrict__ CoutF,
        int M, int N, int K, long ldcT) {
    __shared__ ushort Al[128][40];   // row stride 80B
    __shared__ ushort Bl[128][40];
    int bm = blockIdx.y * 128, bnn = blockIdx.x * 128;
    int tid = threadIdx.x;
    int w = tid >> 6, l = tid & 63;
    int wm = w >> 1, wn = w & 1;
    int sr = tid >> 2, skq = (tid & 3) * 8;
    f32x4 acc[4][4] = {};
    for (int k0 = 0; k0 < K; k0 += 32) {
        *(u16x8*)&Al[sr][skq]      = *(const u16x8*)&A [(long)(bm + sr) * K + k0 + skq];
        *(u16x8*)&Al[sr + 64][skq] = *(const u16x8*)&A [(long)(bm + sr + 64) * K + k0 + skq];
        *(u16x8*)&Bl[sr][skq]      = *(const u16x8*)&Wt[(long)(bnn + sr) * K + k0 + skq];
        *(u16x8*)&Bl[sr + 64][skq] = *(const u16x8*)&Wt[(long)(bnn + sr + 64) * K + k0 + skq];
        __syncthreads();
        s16x8 af[4], bf[4];
        #pragma unroll
        for (int mi = 0; mi < 4; ++mi)
            af[mi] = *(const s16x8*)&Al[wm * 64 + mi * 16 + (l & 15)][(l >> 4) * 8];
        #pragma unroll
        for (int ni = 0; ni < 4; ++ni)
            bf[ni] = *(const s16x8*)&Bl[wn * 64 + ni * 16 + (l & 15)][(l >> 4) * 8];
        #pragma unroll
        for (int mi = 0; mi < 4; ++mi)
            #pragma unroll
            for (int ni = 0; ni < 4; ++ni)
                acc[mi][ni] = __builtin_amdgcn_mfma_f32_16x16x32_bf16(af[mi], bf[ni], acc[mi][ni], 0, 0, 0);
        __syncthreads();
    }
    #pragma unroll
    for (int mi = 0; mi < 4; ++mi) {
        int row0 = bm + wm * 64 + mi * 16 + (l >> 4) * 4;
        #pragma unroll
        for (int ni = 0; ni < 4; ++ni) {
            int coln = bnn + wn * 64 + ni * 16 + (l & 15);
            float bv = bias[coln];
            if (OUTMODE == 5) {
                if (coln < 384) {
                    #pragma unroll
                    for (int reg = 0; reg < 4; ++reg)
                        ((float*)CoutF)[(long)(row0 + reg) * HID + coln] = acc[mi][ni][reg] + bv;
                } else if (coln < 1152) {
                    #pragma unroll
                    for (int reg = 0; reg < 4; ++reg)
                        ((ushort*)Cout)[(long)(row0 + reg) * 768 + (coln - 384)] = f2b(acc[mi][ni][reg] + bv);
                } else {
                    u16x4 pk;
                    #pragma unroll
                    for (int reg = 0; reg < 4; ++reg)
                        pk[reg] = f2b(acc[mi][ni][reg] + bv);
                    *(u16x4*)((ushort*)CoutT + (long)(coln - 1152) * ldcT + row0) = pk;
                }
            } else {
                #pragma unroll
                for (int reg = 0; reg < 4; ++reg) {
                    int rowg = row0 + reg;
                    float v = acc[mi][ni][reg] + bv;
                    if (resid) v += resid[(long)rowg * N + coln];
                    if (RELU)  v = fmaxf(v, 0.f);
                    if (OUTMODE == 0) ((float*)Cout)[(long)rowg * N + coln] = v;
                    else              ((ushort*)Cout)[(long)rowg * N + coln] = f2b(v);
                }
            }
        }
    }
}

// ---------------------------------------------------------------- GCN gather + residual + LN (f32)
__global__ void k_gcn_ln(const float* __restrict__ h, const float* __restrict__ xw,
                         const int* __restrict__ knn,
                         const float* __restrict__ lns, const float* __restrict__ lnb,
                         float* __restrict__ hlocal) {
    int bn = blockIdx.x; int b = bn >> 10;
    __shared__ int nb[KNN];
    __shared__ float red[128];
    int tid = threadIdx.x;
    if (tid < KNN) nb[tid] = knn[(long)bn * KNN + tid];
    __syncthreads();
    float val[3]; float sum = 0.f, ssq = 0.f;
    #pragma unroll
    for (int i = 0; i < 3; ++i) {
        int c = tid + i * 128;
        float acc = xw[(long)bn * HID + c];
        #pragma unroll
        for (int j = 0; j < KNN; ++j)
            acc += xw[((long)(b << 10) + nb[j]) * HID + c];
        float v = h[(long)bn * HID + c] + acc * (1.0f / 17.0f);
        val[i] = v; sum += v; ssq += v * v;
    }
    red[tid] = sum; __syncthreads();
    for (int s = 64; s > 0; s >>= 1) { if (tid < s) red[tid] += red[tid+s]; __syncthreads(); }
    sum = red[0]; __syncthreads();
    red[tid] = ssq; __syncthreads();
    for (int s = 64; s > 0; s >>= 1) { if (tid < s) red[tid] += red[tid+s]; __syncthreads(); }
    ssq = red[0];
    float mu = sum / HID;
    float var = ssq / HID - mu * mu;
    float inv = rsqrtf(var + 1e-5f);
    #pragma unroll
    for (int i = 0; i < 3; ++i) {
        int c = tid + i * 128;
        hlocal[(long)bn * HID + c] = (val[i] - mu) * inv * lns[c] + lnb[c];
    }
}

// ---------------------------------------------------------------- (a[+badd]) -> LN -> (+post), + bf16 mirror
__global__ void k_addln(const float* __restrict__ a, const float* __restrict__ badd,
                        const float* __restrict__ post,
                        const float* __restrict__ lns, const float* __restrict__ lnb,
                        float* __restrict__ outp, ushort* __restrict__ bfout) {
    int bn = blockIdx.x;
    __shared__ float red[128];
    int tid = threadIdx.x;
    float val[3]; float sum = 0.f, ssq = 0.f;
    #pragma unroll
    for (int i = 0; i < 3; ++i) {
        int c = tid + i * 128;
        float v = a[(long)bn * HID + c];
        if (badd) v += badd[(long)bn * HID + c];
        val[i] = v; sum += v; ssq += v * v;
    }
    red[tid] = sum; __syncthreads();
    for (int s = 64; s > 0; s >>= 1) { if (tid < s) red[tid] += red[tid+s]; __syncthreads(); }
    sum = red[0]; __syncthreads();
    red[tid] = ssq; __syncthreads();
    for (int s = 64; s > 0; s >>= 1) { if (tid < s) red[tid] += red[tid+s]; __syncthreads(); }
    ssq = red[0];
    float mu = sum / HID;
    float var = ssq / HID - mu * mu;
    float inv = rsqrtf(var + 1e-5f);
    #pragma unroll
    for (int i = 0; i < 3; ++i) {
        int c = tid + i * 128;
        float o = (val[i] - mu) * inv * lns[c] + lnb[c];
        if (post) o += post[(long)bn * HID + c];
        outp[(long)bn * HID + c] = o;
        if (bfout) bfout[(long)bn * HID + c] = f2b(o);
    }
}

// ---------------------------------------------------------------- MFMA attention (staged, R10 config)
// LDS-staged K/V tiles; strides 136/72 elems = odd multiples of 16B (aligned b128,
// 2-way-free reads). Measured 66.5us in R10.
__global__ __launch_bounds__(256) void k_attn(const ushort* __restrict__ qk,
                                              const ushort* __restrict__ vt,
                                              ushort* __restrict__ o) {
    int b = blockIdx.z, hh = blockIdx.y, r0 = blockIdx.x * 16;
    __shared__ ushort sc[16][1032];     // bf16 scores/probs; stride 2064B
    __shared__ ushort kvt[9216];        // union: Kt[64][136] | VtT[128][72]
    __shared__ float rowinv[16];
    int tid = threadIdx.x;
    int w = tid >> 6, l = tid & 63;
    s16x8 aq[4];
    const ushort* qrow = qk + ((long)(b * N_) + r0 + (l & 15)) * 768 + hh * DH + (l >> 4) * 8;
    #pragma unroll
    for (int ks = 0; ks < 4; ++ks) aq[ks] = *(const s16x8*)(qrow + ks * 32);
    const float scale = 0.08838834764831845f;   // 1/sqrt(128)
    // ---------- S = Q K^T
    for (int m0 = 0; m0 < N_; m0 += 64) {
        {   // stage K tile [64 keys][128 dh] -> Kt[key][136]
            int key = tid >> 2, seg = tid & 3;
            const ushort* src = qk + ((long)(b * N_) + m0 + key) * 768 + 384 + hh * DH + seg * 32;
            ushort* dst = &kvt[key * 136 + seg * 32];
            #pragma unroll
            for (int i = 0; i < 4; ++i)
                *(u16x8*)(dst + i * 8) = *(const u16x8*)(src + i * 8);
        }
        __syncthreads();
        f32x4 acc = {0.f, 0.f, 0.f, 0.f};
        #pragma unroll
        for (int ks = 0; ks < 4; ++ks) {
            s16x8 bk = *(const s16x8*)&kvt[(w * 16 + (l & 15)) * 136 + ks * 32 + (l >> 4) * 8];
            acc = __builtin_amdgcn_mfma_f32_16x16x32_bf16(aq[ks], bk, acc, 0, 0, 0);
        }
        int key = m0 + w * 16 + (l & 15);
        #pragma unroll
        for (int reg = 0; reg < 4; ++reg)
            sc[(l >> 4) * 4 + reg][key] = f2b(acc[reg] * scale);
        __syncthreads();
    }
    // ---------- softmax (32-lane group per row, registers + shfl)
    {
        int g = tid >> 5, l2 = tid & 31;
        #pragma unroll
        for (int rr = 0; rr < 2; ++rr) {
            int row = g + rr * 8;
            float v[32];
            #pragma unroll
            for (int i = 0; i < 16; ++i) {
                uint u = *(const uint*)&sc[row][l2 * 2 + i * 64];
                v[2*i]   = b2f(u & 0xffffu);
                v[2*i+1] = b2f(u >> 16);
            }
            float mx = v[0];
            #pragma unroll
            for (int i = 1; i < 32; ++i) mx = fmaxf(mx, v[i]);
            #pragma unroll
            for (int m = 16; m >= 1; m >>= 1) mx = fmaxf(mx, __shfl_xor(mx, m));
            float sm = 0.f;
            #pragma unroll
            for (int i = 0; i < 16; ++i) {
                float e0 = __expf(v[2*i]   - mx);
                float e1 = __expf(v[2*i+1] - mx);
                sm += e0 + e1;
                *(uint*)&sc[row][l2 * 2 + i * 64] = (uint)f2b(e0) | ((uint)f2b(e1) << 16);
            }
            #pragma unroll
            for (int m = 16; m >= 1; m >>= 1) sm += __shfl_xor(sm, m);
            if (l2 == 0) rowinv[row] = 1.0f / sm;
        }
    }
    __syncthreads();
    // ---------- O = P V
    f32x4 zero = {0.f, 0.f, 0.f, 0.f};
    f32x4 oacc[2] = {zero, zero};
    for (int m0 = 0; m0 < N_; m0 += 64) {
        {   // stage V^T tile [128 dims][64 keys] -> VtT[dim][72]
            int dim = tid >> 1, half = tid & 1;
            const ushort* src = vt + ((long)(hh * DH + dim)) * (B_ * N_) + b * N_ + m0 + half * 32;
            ushort* dst = &kvt[dim * 72 + half * 32];
            #pragma unroll
            for (int i = 0; i < 4; ++i)
                *(u16x8*)(dst + i * 8) = *(const u16x8*)(src + i * 8);
        }
        __syncthreads();
        #pragma unroll
        for (int ks = 0; ks < 2; ++ks) {
            s16x8 pf = *(const s16x8*)&sc[l & 15][m0 + ks * 32 + (l >> 4) * 8];
            #pragma unroll
            for (int d = 0; d < 2; ++d) {
                s16x8 vf = *(const s16x8*)&kvt[((w * 2 + d) * 16 + (l & 15)) * 72 + ks * 32 + (l >> 4) * 8];
                oacc[d] = __builtin_amdgcn_mfma_f32_16x16x32_bf16(pf, vf, oacc[d], 0, 0, 0);
            }
        }
        __syncthreads();
    }
    #pragma unroll
    for (int d = 0; d < 2; ++d) {
        int dim = (w * 2 + d) * 16 + (l & 15);
        #pragma unroll
        for (int reg = 0; reg < 4; ++reg) {
            int row = (l >> 4) * 4 + reg;
            o[((long)(b * N_) + r0 + row) * HID + hh * DH + dim] = f2b(oacc[d][reg] * rowinv[row]);
        }
    }
}

// ---------------------------------------------------------------- mean pool, two-stage
__global__ __launch_bounds__(384) void k_pool1(const float* __restrict__ h,
                                               float* __restrict__ partial) {
    int s = blockIdx.x, b = blockIdx.y;
    int c = threadIdx.x;
    const float* hp = h + ((long)(b * N_) + s * 32) * HID + c;
    float acc = 0.f;
    #pragma unroll
    for (int n = 0; n < 32; ++n) acc += hp[(long)n * HID];
    partial[((long)(b * 32) + s) * HID + c] = acc;
}
__global__ __launch_bounds__(384) void k_pool2(const float* __restrict__ partial,
                                               float* __restrict__ pooled) {
    int b = blockIdx.x;
    int c = threadIdx.x;
    const float* pp = partial + (long)(b * 32) * HID + c;
    float acc = 0.f;
    #pragma unroll
    for (int s = 0; s < 32; ++s) acc += pp[(long)s * HID];
    pooled[b * HID + c] = acc * (1.0f / N_);
}

// ---------------------------------------------------------------- head (f32)
__global__ void k_head(const float* __restrict__ pooled,
                       const float* __restrict__ w1, const float* __restrict__ b1,
                       const float* __restrict__ w2, const float* __restrict__ b2,
                       float* __restrict__ out) {
    int b = blockIdx.x; int tid = threadIdx.x;   // 384 threads
    __shared__ float z[HID];
    float acc = b1[tid];
    for (int c = 0; c < HID; ++c) acc += pooled[b * HID + c] * w1[c * HID + tid];
    z[tid] = fmaxf(acc, 0.f);
    __syncthreads();
    if (tid < OUTD) {
        float a2 = b2[tid];
        for (int j = 0; j < HID; ++j) a2 += z[j] * w2[j * OUTD + tid];
        out[b * OUTD + tid] = a2;
    }
}

// ================================================================ launch
extern "C" void kernel_launch(void* const* d_in, const int* in_sizes, int n_in,
                              void* d_out, int out_size, void* d_ws, size_t ws_size,
                              hipStream_t stream) {
    const float* x       = (const float*)d_in[0];
    const float* W_enc   = (const float*)d_in[1];
    const float* b_enc   = (const float*)d_in[2];
    const float* gcn_W   = (const float*)d_in[3];
    const float* gcn_b   = (const float*)d_in[4];
    const float* Wq      = (const float*)d_in[5];
    const float* bq      = (const float*)d_in[6];
    const float* Wk      = (const float*)d_in[7];
    const float* bk      = (const float*)d_in[8];
    const float* Wv      = (const float*)d_in[9];
    const float* bv      = (const float*)d_in[10];
    const float* Wo      = (const float*)d_in[11];
    const float* bo      = (const float*)d_in[12];
    const float* ln_s    = (const float*)d_in[13];
    const float* ln_b    = (const float*)d_in[14];
    const float* mlp_W1  = (const float*)d_in[15];
    const float* mlp_b1  = (const float*)d_in[16];
    const float* mlp_W2  = (const float*)d_in[17];
    const float* mlp_b2  = (const float*)d_in[18];
    const float* lin1_W  = (const float*)d_in[19];
    const float* lin1_b  = (const float*)d_in[20];
    const float* lin2_W  = (const float*)d_in[21];
    const float* lin2_b  = (const float*)d_in[22];

    const long S = (long)B_ * N_ * HID;            // 3,145,728
    char* base = (char*)d_ws;
    float* h      = (float*)(base);
    float* tmp1   = (float*)(base + (size_t)S * 4);       // xw / attn-out(bf16) / u / pool-partial / nhh+nhl
    float* hlocal = (float*)(base + (size_t)S * 8);
    float* outb   = (float*)(base + (size_t)S * 12);
    char*  tzone  = base + (size_t)S * 16;                // 8S-byte multi-use region
    float* proj   = (float*)(base + (size_t)S * 24);
    float*  sim = (float*)tzone;                          // phase-1 (spills into proj)
    ushort* qkbf = (ushort*)tzone;                        // [0,4S): fused q|k rows stride 768
    ushort* vbT  = (ushort*)(tzone + (size_t)S * 4);      // [4S,6S)
    ushort* outb_bf = (ushort*)(tzone + (size_t)S * 6);   // [6S,8S)
    ushort* tb  = (ushort*)tzone;                         // [0,4S) after attn (mlp hidden)
    ushort* nhh = (ushort*)(base + (size_t)S * 4);        // phase-1 overlay of tmp1
    ushort* nhl = (ushort*)(base + (size_t)S * 6);
    int*    knn    = (int*)(base + (size_t)S * 28);
    float*  pooled = (float*)(base + (size_t)S * 28 + 524288);
    ushort* wts    = (ushort*)(base + (size_t)S * 28 + 524288 + 16384);
    const long SQ = (long)HID * HID;
    ushort* w1T = wts + 15 * SQ;
    ushort* w2T = w1T + 3 * (long)HID * 2 * HID;
    ushort* hb  = (ushort*)(base + (size_t)S * 28 + 524288 + 16384 + 7962624);
    float* gqkvb = (float*)(base + (size_t)S * 28 + 524288 + 16384 + 7962624 + (size_t)S * 2);
    float* partial = tmp1;
    ushort* obf = (ushort*)tmp1;                          // attn bf16 out (tmp1 dead)

    // ---- weight cast+transpose (bf16 [N][K]) + bias concat
    k_cast15<<<dim3(12, 12, 15), 256, 0, stream>>>(gcn_W, Wq, Wk, Wv, Wo, wts);
    k_castT<<<dim3(24, 12, 3), 256, 0, stream>>>(mlp_W1, w1T, HID, 2 * HID);
    k_castT<<<dim3(12, 24, 3), 256, 0, stream>>>(mlp_W2, w2T, 2 * HID, HID);
    k_biasgqkv<<<3, 384, 0, stream>>>(gcn_b, bq, bk, bv, gqkvb);

    // ---- encode(+normalize+mirrors) + sim (hi/lo MFMA) + topk
    k_encode<<<B_ * N_, 128, 0, stream>>>(x, W_enc, b_enc, h, hb, nhh, nhl);
    k_sim<<<dim3(8, 8, 8), 256, 0, stream>>>(nhh, nhl, sim);
    k_topk<<<B_ * N_ / 4, 256, 0, stream>>>(sim, knn);

    const int M = B_ * N_;   // 8192
    for (int l = 0; l < L_; ++l) {
        const ushort* gqkvW = wts + (long)(l * 4) * SQ;       // [gcn|q|k|v] rows [1536][384]
        const ushort* woT   = wts + (long)(12 + l) * SQ;
        const ushort* w1Tl = w1T + (long)l * HID * 2 * HID;
        const ushort* w2Tl = w2T + (long)l * HID * 2 * HID;
        const float* bol = bo + (long)l * HID;
        const float* b1l = mlp_b1 + (long)l * 2 * HID;
        const float* b2l = mlp_b2 + (long)l * HID;
        const float* ls0 = ln_s + (long)(l * 3 + 0) * HID; const float* lb0 = ln_b + (long)(l * 3 + 0) * HID;
        const float* ls1 = ln_s + (long)(l * 3 + 1) * HID; const float* lb1 = ln_b + (long)(l * 3 + 1) * HID;
        const float* ls2 = ln_s + (long)(l * 3 + 2) * HID; const float* lb2 = ln_b + (long)(l * 3 + 2) * HID;

        // fused xw|q|k|v: one GEMM, N=1536 (xw f32 -> tmp1; q/k bf16 rows 768; v transposed)
        k_mgemm<5, false><<<dim3(1536 / 128, M / 128), 256, 0, stream>>>(
            hb, gqkvW, gqkvb + l * 1536, nullptr, qkbf, vbT, tmp1, M, 1536, HID, (long)M);
        k_gcn_ln<<<B_ * N_, 128, 0, stream>>>(h, tmp1, knn, ls0, lb0, hlocal);
        // attention -> obf (bf16)
        k_attn<<<dim3(N_ / 16, NHEADS, B_), 256, 0, stream>>>(qkbf, vbT, obf);
        // proj = o @ Wo + bo (f32)
        k_mgemm<0, false><<<dim3(HID / 128, M / 128), 256, 0, stream>>>(
            obf, woT, bol, nullptr, proj, nullptr, nullptr, M, HID, HID, 0);
        // out = hlocal + LN(h + proj) -> outb (+bf16 mirror)
        k_addln<<<B_ * N_, 128, 0, stream>>>(h, proj, hlocal, ls1, lb1, outb, outb_bf);
        // t = relu(out @ W1 + b1) -> bf16 tb
        k_mgemm<1, true><<<dim3(2 * HID / 128, M / 128), 256, 0, stream>>>(
            outb_bf, w1Tl, b1l, nullptr, tb, nullptr, nullptr, M, 2 * HID, HID, 0);
        // u = out + t @ W2 + b2 -> tmp1 (f32)
        k_mgemm<0, false><<<dim3(HID / 128, M / 128), 256, 0, stream>>>(
            tb, w2Tl, b2l, outb, tmp1, nullptr, nullptr, M, HID, 2 * HID, 0);
        // h = LN(u) (+hb mirror)
        k_addln<<<B_ * N_, 128, 0, stream>>>(tmp1, nullptr, nullptr, ls2, lb2, h, hb);
    }

    k_pool1<<<dim3(32, B_), 384, 0, stream>>>(h, partial);
    k_pool2<<<B_, 384, 0, stream>>>(partial, pooled);
    k_head<<<B_, HID, 0, stream>>>(pooled, lin1_W, lin1_b, lin2_W, lin2_b,
                                   (float*)d_out);
}

// Round 15
// 814.536 us; speedup vs baseline: 1.2141x; 1.0236x over previous
//
#include <hip/hip_runtime.h>
#include <hip/hip_bf16.h>

#define B_    8
#define C_    64
#define N_    1024
#define HID   384
#define OUTD  128
#define L_    3
#define KNN   16
#define NHEADS 3
#define DH    128

typedef __attribute__((ext_vector_type(8))) short    s16x8;   // MFMA A/B frag: 8 bf16
typedef __attribute__((ext_vector_type(4))) float    f32x4;   // MFMA C/D frag
typedef __attribute__((ext_vector_type(8))) unsigned short u16x8;
typedef __attribute__((ext_vector_type(4))) unsigned short u16x4;

// RNE f32 -> bf16 (finite inputs)
__device__ __forceinline__ ushort f2b(float f) {
    uint x = __float_as_uint(f);
    return (ushort)((x + 0x7fff + ((x >> 16) & 1)) >> 16);
}
__device__ __forceinline__ float b2f(uint u) {
    return __uint_as_float(u << 16);
}

// ---------------------------------------------------------------- encode (+normalize +bf16 mirrors)
__global__ void k_encode(const float* __restrict__ x, const float* __restrict__ Wenc,
                         const float* __restrict__ benc, float* __restrict__ h,
                         ushort* __restrict__ hb,
                         ushort* __restrict__ nhh, ushort* __restrict__ nhl) {
    int bn = blockIdx.x;
    int b = bn >> 10;
    const float* xb = x + (long)b * C_ * N_ + (bn & 1023);
    int tid = threadIdx.x;
    __shared__ float red[128];
    float val[3];
    #pragma unroll
    for (int i = 0; i < 3; ++i) {
        int c0 = tid + i * 128;
        float acc = benc[c0];
        for (int c = 0; c < C_; ++c)
            acc += xb[c * N_] * Wenc[c * HID + c0];
        h[(long)bn * HID + c0] = acc;
        hb[(long)bn * HID + c0] = f2b(acc);
        val[i] = acc;
    }
    float ss = 0.f;
    #pragma unroll
    for (int i = 0; i < 3; ++i) ss += val[i] * val[i];
    red[tid] = ss; __syncthreads();
    for (int s = 64; s > 0; s >>= 1) { if (tid < s) red[tid] += red[tid+s]; __syncthreads(); }
    float inv = 1.0f / sqrtf(red[0]);
    #pragma unroll
    for (int i = 0; i < 3; ++i) {
        int c0 = tid + i * 128;
        float fv = val[i] * inv;
        ushort hu = f2b(fv);
        float lo = fv - b2f((uint)hu);
        nhh[(long)bn * HID + c0] = hu;
        nhl[(long)bn * HID + c0] = f2b(lo);
    }
}

// ---------------------------------------------------------------- sim = nh @ nh^T via hi/lo split MFMA
__global__ __launch_bounds__(256) void k_sim(const ushort* __restrict__ nhh,
                                             const ushort* __restrict__ nhl,
                                             float* __restrict__ sim) {
    __shared__ ushort Ah[128][40], Alo[128][40], Bh[128][40], Blo[128][40];
    int bz = blockIdx.z;
    int bm = blockIdx.y * 128, bn = blockIdx.x * 128;
    const ushort* baseh = nhh + (long)bz * N_ * HID;
    const ushort* basel = nhl + (long)bz * N_ * HID;
    int tid = threadIdx.x;
    int w = tid >> 6, l = tid & 63;
    int wm = w >> 1, wn = w & 1;
    int sr = tid >> 2, skq = (tid & 3) * 8;
    f32x4 acc[4][4] = {};
    for (int k0 = 0; k0 < HID; k0 += 32) {
        *(u16x8*)&Ah [sr][skq]      = *(const u16x8*)&baseh[(long)(bm + sr) * HID + k0 + skq];
        *(u16x8*)&Ah [sr + 64][skq] = *(const u16x8*)&baseh[(long)(bm + sr + 64) * HID + k0 + skq];
        *(u16x8*)&Alo[sr][skq]      = *(const u16x8*)&basel[(long)(bm + sr) * HID + k0 + skq];
        *(u16x8*)&Alo[sr + 64][skq] = *(const u16x8*)&basel[(long)(bm + sr + 64) * HID + k0 + skq];
        *(u16x8*)&Bh [sr][skq]      = *(const u16x8*)&baseh[(long)(bn + sr) * HID + k0 + skq];
        *(u16x8*)&Bh [sr + 64][skq] = *(const u16x8*)&baseh[(long)(bn + sr + 64) * HID + k0 + skq];
        *(u16x8*)&Blo[sr][skq]      = *(const u16x8*)&basel[(long)(bn + sr) * HID + k0 + skq];
        *(u16x8*)&Blo[sr + 64][skq] = *(const u16x8*)&basel[(long)(bn + sr + 64) * HID + k0 + skq];
        __syncthreads();
        s16x8 ah[4], al[4], bh[4], bl[4];
        #pragma unroll
        for (int mi = 0; mi < 4; ++mi) {
            ah[mi] = *(const s16x8*)&Ah [wm * 64 + mi * 16 + (l & 15)][(l >> 4) * 8];
            al[mi] = *(const s16x8*)&Alo[wm * 64 + mi * 16 + (l & 15)][(l >> 4) * 8];
        }
        #pragma unroll
        for (int ni = 0; ni < 4; ++ni) {
            bh[ni] = *(const s16x8*)&Bh [wn * 64 + ni * 16 + (l & 15)][(l >> 4) * 8];
            bl[ni] = *(const s16x8*)&Blo[wn * 64 + ni * 16 + (l & 15)][(l >> 4) * 8];
        }
        #pragma unroll
        for (int mi = 0; mi < 4; ++mi)
            #pragma unroll
            for (int ni = 0; ni < 4; ++ni) {
                acc[mi][ni] = __builtin_amdgcn_mfma_f32_16x16x32_bf16(ah[mi], bh[ni], acc[mi][ni], 0, 0, 0);
                acc[mi][ni] = __builtin_amdgcn_mfma_f32_16x16x32_bf16(ah[mi], bl[ni], acc[mi][ni], 0, 0, 0);
                acc[mi][ni] = __builtin_amdgcn_mfma_f32_16x16x32_bf16(al[mi], bh[ni], acc[mi][ni], 0, 0, 0);
            }
        __syncthreads();
    }
    float* so = sim + (long)bz * N_ * N_;
    #pragma unroll
    for (int mi = 0; mi < 4; ++mi) {
        int row0 = bm + wm * 64 + mi * 16 + (l >> 4) * 4;
        #pragma unroll
        for (int ni = 0; ni < 4; ++ni) {
            int coln = bn + wn * 64 + ni * 16 + (l & 15);
            #pragma unroll
            for (int reg = 0; reg < 4; ++reg)
                so[(long)(row0 + reg) * N_ + coln] = acc[mi][ni][reg];
        }
    }
}

// ---------------------------------------------------------------- top-k (k=16), one wave per row
__global__ __launch_bounds__(256) void k_topk(const float* __restrict__ sim, int* __restrict__ knn) {
    int tid = threadIdx.x;
    int wave = tid >> 6, ll = tid & 63;
    int bn = blockIdx.x * 4 + wave;
    int b = bn >> 10, n = bn & 1023;
    const float* row = sim + (long)b * N_ * N_ + (long)n * N_;
    float v[16];
    #pragma unroll
    for (int j = 0; j < 16; ++j) {
        int m = ll + j * 64;
        v[j] = row[m] - (m == n ? 2.0f : 0.0f);
    }
    int* kout = knn + (long)bn * KNN;
    for (int it = 0; it < KNN; ++it) {
        float bv = v[0]; int bi = ll;
        #pragma unroll
        for (int j = 1; j < 16; ++j)
            if (v[j] > bv) { bv = v[j]; bi = ll + j * 64; }
        #pragma unroll
        for (int mask = 1; mask < 64; mask <<= 1) {
            float ov = __shfl_xor(bv, mask);
            int   oi = __shfl_xor(bi, mask);
            if (ov > bv || (ov == bv && oi < bi)) { bv = ov; bi = oi; }
        }
        if (ll == 0) kout[it] = bi;
        if ((bi & 63) == ll) v[bi >> 6] = -1e30f;
    }
}

// ---------------------------------------------------------------- weight cast+transpose
// slots: layer l -> [gcn|q|k|v] at l*4+{0,1,2,3} (contiguous per layer) ; o -> 12+l
__global__ void k_cast15(const float* __restrict__ g, const float* __restrict__ q,
                         const float* __restrict__ k, const float* __restrict__ v,
                         const float* __restrict__ o, ushort* __restrict__ out) {
    int z = blockIdx.z; int type = z / 3, l = z % 3;
    const float* in = (type == 0 ? g : type == 1 ? q : type == 2 ? k : type == 3 ? v : o)
                      + (long)l * HID * HID;
    int slot = (type == 4) ? 12 + l : l * 4 + type;
    ushort* op = out + (long)slot * HID * HID;
    __shared__ float t[32][33];
    int c0 = blockIdx.x * 32, r0 = blockIdx.y * 32;
    int tid = threadIdx.x; int i = tid & 31, j4 = tid >> 5;
    #pragma unroll
    for (int rr = 0; rr < 4; ++rr) {
        int r = j4 * 4 + rr;
        t[r][i] = in[(long)(r0 + r) * HID + c0 + i];
    }
    __syncthreads();
    #pragma unroll
    for (int rr = 0; rr < 4; ++rr) {
        int c = j4 * 4 + rr;
        op[(long)(c0 + c) * HID + r0 + i] = f2b(t[i][c]);
    }
}

__global__ void k_castT(const float* __restrict__ in_, ushort* __restrict__ out_,
                        int R, int C) {
    long mz = (long)blockIdx.z * R * C;
    const float* in = in_ + mz;
    ushort* op = out_ + mz;
    __shared__ float t[32][33];
    int c0 = blockIdx.x * 32, r0 = blockIdx.y * 32;
    int tid = threadIdx.x; int i = tid & 31, j4 = tid >> 5;
    #pragma unroll
    for (int rr = 0; rr < 4; ++rr) {
        int r = j4 * 4 + rr;
        t[r][i] = in[(long)(r0 + r) * C + c0 + i];
    }
    __syncthreads();
    #pragma unroll
    for (int rr = 0; rr < 4; ++rr) {
        int c = j4 * 4 + rr;
        op[(long)(c0 + c) * R + r0 + i] = f2b(t[i][c]);
    }
}

// concat biases: out[l][0:384)=gcn_b, [384:768)=bq, [768:1152)=bk, [1152:1536)=bv
__global__ void k_biasgqkv(const float* __restrict__ gb, const float* __restrict__ bq,
                           const float* __restrict__ bk, const float* __restrict__ bv,
                           float* __restrict__ out) {
    int l = blockIdx.x, t = threadIdx.x;
    out[l * 1536 + t]        = gb[l * HID + t];
    out[l * 1536 + 384 + t]  = bq[l * HID + t];
    out[l * 1536 + 768 + t]  = bk[l * HID + t];
    out[l * 1536 + 1152 + t] = bv[l * HID + t];
}

// ---------------------------------------------------------------- MFMA GEMM v2 (128x128 tile)
// OUTMODE: 0 = f32 [M][N], 1 = bf16 [M][N],
//          5 = fused gcn|q|k|v: coln<384 -> f32 CoutF [M][384]; 384..1152 -> bf16 Cout rows
//              stride 768 at coln-384; >=1152 -> transposed CoutT [384][ldcT] at coln-1152
template<int OUTMODE, bool RELU>
__global__ __launch_bounds__(256) void k_mgemm(
        const ushort* __restrict__ A, const ushort* __restrict__ Wt,
        const float* __restrict__ bias, const float* __restrict__ resid,
        void* __restrict__ Cout, void* __restrict__ CoutT, void* __restrict__ CoutF,
        int M, int N, int K, long ldcT) {
    __shared__ ushort Al[128][40];   // row stride 80B
    __shared__ ushort Bl[128][40];
    int bm = blockIdx.y * 128, bnn = blockIdx.x * 128;
    int tid = threadIdx.x;
    int w = tid >> 6, l = tid & 63;
    int wm = w >> 1, wn = w & 1;
    int sr = tid >> 2, skq = (tid & 3) * 8;
    f32x4 acc[4][4] = {};
    for (int k0 = 0; k0 < K; k0 += 32) {
        *(u16x8*)&Al[sr][skq]      = *(const u16x8*)&A [(long)(bm + sr) * K + k0 + skq];
        *(u16x8*)&Al[sr + 64][skq] = *(const u16x8*)&A [(long)(bm + sr + 64) * K + k0 + skq];
        *(u16x8*)&Bl[sr][skq]      = *(const u16x8*)&Wt[(long)(bnn + sr) * K + k0 + skq];
        *(u16x8*)&Bl[sr + 64][skq] = *(const u16x8*)&Wt[(long)(bnn + sr + 64) * K + k0 + skq];
        __syncthreads();
        s16x8 af[4], bf[4];
        #pragma unroll
        for (int mi = 0; mi < 4; ++mi)
            af[mi] = *(const s16x8*)&Al[wm * 64 + mi * 16 + (l & 15)][(l >> 4) * 8];
        #pragma unroll
        for (int ni = 0; ni < 4; ++ni)
            bf[ni] = *(const s16x8*)&Bl[wn * 64 + ni * 16 + (l & 15)][(l >> 4) * 8];
        #pragma unroll
        for (int mi = 0; mi < 4; ++mi)
            #pragma unroll
            for (int ni = 0; ni < 4; ++ni)
                acc[mi][ni] = __builtin_amdgcn_mfma_f32_16x16x32_bf16(af[mi], bf[ni], acc[mi][ni], 0, 0, 0);
        __syncthreads();
    }
    #pragma unroll
    for (int mi = 0; mi < 4; ++mi) {
        int row0 = bm + wm * 64 + mi * 16 + (l >> 4) * 4;
        #pragma unroll
        for (int ni = 0; ni < 4; ++ni) {
            int coln = bnn + wn * 64 + ni * 16 + (l & 15);
            float bv = bias[coln];
            if (OUTMODE == 5) {
                if (coln < 384) {
                    #pragma unroll
                    for (int reg = 0; reg < 4; ++reg)
                        ((float*)CoutF)[(long)(row0 + reg) * HID + coln] = acc[mi][ni][reg] + bv;
                } else if (coln < 1152) {
                    #pragma unroll
                    for (int reg = 0; reg < 4; ++reg)
                        ((ushort*)Cout)[(long)(row0 + reg) * 768 + (coln - 384)] = f2b(acc[mi][ni][reg] + bv);
                } else {
                    u16x4 pk;
                    #pragma unroll
                    for (int reg = 0; reg < 4; ++reg)
                        pk[reg] = f2b(acc[mi][ni][reg] + bv);
                    *(u16x4*)((ushort*)CoutT + (long)(coln - 1152) * ldcT + row0) = pk;
                }
            } else {
                #pragma unroll
                for (int reg = 0; reg < 4; ++reg) {
                    int rowg = row0 + reg;
                    float v = acc[mi][ni][reg] + bv;
                    if (resid) v += resid[(long)rowg * N + coln];
                    if (RELU)  v = fmaxf(v, 0.f);
                    if (OUTMODE == 0) ((float*)Cout)[(long)rowg * N + coln] = v;
                    else              ((ushort*)Cout)[(long)rowg * N + coln] = f2b(v);
                }
            }
        }
    }
}

// ---------------------------------------------------------------- GCN gather + residual + LN (f32)
__global__ void k_gcn_ln(const float* __restrict__ h, const float* __restrict__ xw,
                         const int* __restrict__ knn,
                         const float* __restrict__ lns, const float* __restrict__ lnb,
                         float* __restrict__ hlocal) {
    int bn = blockIdx.x; int b = bn >> 10;
    __shared__ int nb[KNN];
    __shared__ float red[128];
    int tid = threadIdx.x;
    if (tid < KNN) nb[tid] = knn[(long)bn * KNN + tid];
    __syncthreads();
    float val[3]; float sum = 0.f, ssq = 0.f;
    #pragma unroll
    for (int i = 0; i < 3; ++i) {
        int c = tid + i * 128;
        float acc = xw[(long)bn * HID + c];
        #pragma unroll
        for (int j = 0; j < KNN; ++j)
            acc += xw[((long)(b << 10) + nb[j]) * HID + c];
        float v = h[(long)bn * HID + c] + acc * (1.0f / 17.0f);
        val[i] = v; sum += v; ssq += v * v;
    }
    red[tid] = sum; __syncthreads();
    for (int s = 64; s > 0; s >>= 1) { if (tid < s) red[tid] += red[tid+s]; __syncthreads(); }
    sum = red[0]; __syncthreads();
    red[tid] = ssq; __syncthreads();
    for (int s = 64; s > 0; s >>= 1) { if (tid < s) red[tid] += red[tid+s]; __syncthreads(); }
    ssq = red[0];
    float mu = sum / HID;
    float var = ssq / HID - mu * mu;
    float inv = rsqrtf(var + 1e-5f);
    #pragma unroll
    for (int i = 0; i < 3; ++i) {
        int c = tid + i * 128;
        hlocal[(long)bn * HID + c] = (val[i] - mu) * inv * lns[c] + lnb[c];
    }
}

// ---------------------------------------------------------------- (a[+badd]) -> LN -> (+post), + bf16 mirror
__global__ void k_addln(const float* __restrict__ a, const float* __restrict__ badd,
                        const float* __restrict__ post,
                        const float* __restrict__ lns, const float* __restrict__ lnb,
                        float* __restrict__ outp, ushort* __restrict__ bfout) {
    int bn = blockIdx.x;
    __shared__ float red[128];
    int tid = threadIdx.x;
    float val[3]; float sum = 0.f, ssq = 0.f;
    #pragma unroll
    for (int i = 0; i < 3; ++i) {
        int c = tid + i * 128;
        float v = a[(long)bn * HID + c];
        if (badd) v += badd[(long)bn * HID + c];
        val[i] = v; sum += v; ssq += v * v;
    }
    red[tid] = sum; __syncthreads();
    for (int s = 64; s > 0; s >>= 1) { if (tid < s) red[tid] += red[tid+s]; __syncthreads(); }
    sum = red[0]; __syncthreads();
    red[tid] = ssq; __syncthreads();
    for (int s = 64; s > 0; s >>= 1) { if (tid < s) red[tid] += red[tid+s]; __syncthreads(); }
    ssq = red[0];
    float mu = sum / HID;
    float var = ssq / HID - mu * mu;
    float inv = rsqrtf(var + 1e-5f);
    #pragma unroll
    for (int i = 0; i < 3; ++i) {
        int c = tid + i * 128;
        float o = (val[i] - mu) * inv * lns[c] + lnb[c];
        if (post) o += post[(long)bn * HID + c];
        outp[(long)bn * HID + c] = o;
        if (bfout) bfout[(long)bn * HID + c] = f2b(o);
    }
}

// ---------------------------------------------------------------- MFMA attention (staged + XCD swizzle)
// R10's measured-66.5us structure (strides 136/72, 16B-aligned), plus XCD-aware
// block decode: all 64 row-blocks of one (b,h) land on one XCD so its K/V slice
// (~768KB) stays L2-resident. 1D grid of 1536; xcd = bid&7 (round-robin heuristic;
// correctness is mapping-independent).
__global__ __launch_bounds__(256) void k_attn(const ushort* __restrict__ qk,
                                              const ushort* __restrict__ vt,
                                              ushort* __restrict__ o) {
    int bid = blockIdx.x;
    int xcd = bid & 7;
    int j   = bid >> 3;                 // 0..191
    int g   = xcd + 8 * (j % 3);        // bh group 0..23, fixed per XCD
    int r0  = (j / 3) * 16;             // 0..1008
    int b = g / NHEADS, hh = g % NHEADS;
    __shared__ ushort sc[16][1032];     // bf16 scores/probs; stride 2064B
    __shared__ ushort kvt[9216];        // union: Kt[64][136] | VtT[128][72]
    __shared__ float rowinv[16];
    int tid = threadIdx.x;
    int w = tid >> 6, l = tid & 63;
    s16x8 aq[4];
    const ushort* qrow = qk + ((long)(b * N_) + r0 + (l & 15)) * 768 + hh * DH + (l >> 4) * 8;
    #pragma unroll
    for (int ks = 0; ks < 4; ++ks) aq[ks] = *(const s16x8*)(qrow + ks * 32);
    const float scale = 0.08838834764831845f;   // 1/sqrt(128)
    // ---------- S = Q K^T
    for (int m0 = 0; m0 < N_; m0 += 64) {
        {   // stage K tile [64 keys][128 dh] -> Kt[key][136]
            int key = tid >> 2, seg = tid & 3;
            const ushort* src = qk + ((long)(b * N_) + m0 + key) * 768 + 384 + hh * DH + seg * 32;
            ushort* dst = &kvt[key * 136 + seg * 32];
            #pragma unroll
            for (int i = 0; i < 4; ++i)
                *(u16x8*)(dst + i * 8) = *(const u16x8*)(src + i * 8);
        }
        __syncthreads();
        f32x4 acc = {0.f, 0.f, 0.f, 0.f};
        #pragma unroll
        for (int ks = 0; ks < 4; ++ks) {
            s16x8 bk = *(const s16x8*)&kvt[(w * 16 + (l & 15)) * 136 + ks * 32 + (l >> 4) * 8];
            acc = __builtin_amdgcn_mfma_f32_16x16x32_bf16(aq[ks], bk, acc, 0, 0, 0);
        }
        int key = m0 + w * 16 + (l & 15);
        #pragma unroll
        for (int reg = 0; reg < 4; ++reg)
            sc[(l >> 4) * 4 + reg][key] = f2b(acc[reg] * scale);
        __syncthreads();
    }
    // ---------- softmax (32-lane group per row, registers + shfl)
    {
        int g2 = tid >> 5, l2 = tid & 31;
        #pragma unroll
        for (int rr = 0; rr < 2; ++rr) {
            int row = g2 + rr * 8;
            float v[32];
            #pragma unroll
            for (int i = 0; i < 16; ++i) {
                uint u = *(const uint*)&sc[row][l2 * 2 + i * 64];
                v[2*i]   = b2f(u & 0xffffu);
                v[2*i+1] = b2f(u >> 16);
            }
            float mx = v[0];
            #pragma unroll
            for (int i = 1; i < 32; ++i) mx = fmaxf(mx, v[i]);
            #pragma unroll
            for (int m = 16; m >= 1; m >>= 1) mx = fmaxf(mx, __shfl_xor(mx, m));
            float sm = 0.f;
            #pragma unroll
            for (int i = 0; i < 16; ++i) {
                float e0 = __expf(v[2*i]   - mx);
                float e1 = __expf(v[2*i+1] - mx);
                sm += e0 + e1;
                *(uint*)&sc[row][l2 * 2 + i * 64] = (uint)f2b(e0) | ((uint)f2b(e1) << 16);
            }
            #pragma unroll
            for (int m = 16; m >= 1; m >>= 1) sm += __shfl_xor(sm, m);
            if (l2 == 0) rowinv[row] = 1.0f / sm;
        }
    }
    __syncthreads();
    // ---------- O = P V
    f32x4 zero = {0.f, 0.f, 0.f, 0.f};
    f32x4 oacc[2] = {zero, zero};
    for (int m0 = 0; m0 < N_; m0 += 64) {
        {   // stage V^T tile [128 dims][64 keys] -> VtT[dim][72]
            int dim = tid >> 1, half = tid & 1;
            const ushort* src = vt + ((long)(hh * DH + dim)) * (B_ * N_) + b * N_ + m0 + half * 32;
            ushort* dst = &kvt[dim * 72 + half * 32];
            #pragma unroll
            for (int i = 0; i < 4; ++i)
                *(u16x8*)(dst + i * 8) = *(const u16x8*)(src + i * 8);
        }
        __syncthreads();
        #pragma unroll
        for (int ks = 0; ks < 2; ++ks) {
            s16x8 pf = *(const s16x8*)&sc[l & 15][m0 + ks * 32 + (l >> 4) * 8];
            #pragma unroll
            for (int d = 0; d < 2; ++d) {
                s16x8 vf = *(const s16x8*)&kvt[((w * 2 + d) * 16 + (l & 15)) * 72 + ks * 32 + (l >> 4) * 8];
                oacc[d] = __builtin_amdgcn_mfma_f32_16x16x32_bf16(pf, vf, oacc[d], 0, 0, 0);
            }
        }
        __syncthreads();
    }
    #pragma unroll
    for (int d = 0; d < 2; ++d) {
        int dim = (w * 2 + d) * 16 + (l & 15);
        #pragma unroll
        for (int reg = 0; reg < 4; ++reg) {
            int row = (l >> 4) * 4 + reg;
            o[((long)(b * N_) + r0 + row) * HID + hh * DH + dim] = f2b(oacc[d][reg] * rowinv[row]);
        }
    }
}

// ---------------------------------------------------------------- mean pool, two-stage
__global__ __launch_bounds__(384) void k_pool1(const float* __restrict__ h,
                                               float* __restrict__ partial) {
    int s = blockIdx.x, b = blockIdx.y;
    int c = threadIdx.x;
    const float* hp = h + ((long)(b * N_) + s * 32) * HID + c;
    float acc = 0.f;
    #pragma unroll
    for (int n = 0; n < 32; ++n) acc += hp[(long)n * HID];
    partial[((long)(b * 32) + s) * HID + c] = acc;
}
__global__ __launch_bounds__(384) void k_pool2(const float* __restrict__ partial,
                                               float* __restrict__ pooled) {
    int b = blockIdx.x;
    int c = threadIdx.x;
    const float* pp = partial + (long)(b * 32) * HID + c;
    float acc = 0.f;
    #pragma unroll
    for (int s = 0; s < 32; ++s) acc += pp[(long)s * HID];
    pooled[b * HID + c] = acc * (1.0f / N_);
}

// ---------------------------------------------------------------- head (f32)
__global__ void k_head(const float* __restrict__ pooled,
                       const float* __restrict__ w1, const float* __restrict__ b1,
                       const float* __restrict__ w2, const float* __restrict__ b2,
                       float* __restrict__ out) {
    int b = blockIdx.x; int tid = threadIdx.x;   // 384 threads
    __shared__ float z[HID];
    float acc = b1[tid];
    for (int c = 0; c < HID; ++c) acc += pooled[b * HID + c] * w1[c * HID + tid];
    z[tid] = fmaxf(acc, 0.f);
    __syncthreads();
    if (tid < OUTD) {
        float a2 = b2[tid];
        for (int j = 0; j < HID; ++j) a2 += z[j] * w2[j * OUTD + tid];
        out[b * OUTD + tid] = a2;
    }
}

// ================================================================ launch
extern "C" void kernel_launch(void* const* d_in, const int* in_sizes, int n_in,
                              void* d_out, int out_size, void* d_ws, size_t ws_size,
                              hipStream_t stream) {
    const float* x       = (const float*)d_in[0];
    const float* W_enc   = (const float*)d_in[1];
    const float* b_enc   = (const float*)d_in[2];
    const float* gcn_W   = (const float*)d_in[3];
    const float* gcn_b   = (const float*)d_in[4];
    const float* Wq      = (const float*)d_in[5];
    const float* bq      = (const float*)d_in[6];
    const float* Wk      = (const float*)d_in[7];
    const float* bk      = (const float*)d_in[8];
    const float* Wv      = (const float*)d_in[9];
    const float* bv      = (const float*)d_in[10];
    const float* Wo      = (const float*)d_in[11];
    const float* bo      = (const float*)d_in[12];
    const float* ln_s    = (const float*)d_in[13];
    const float* ln_b    = (const float*)d_in[14];
    const float* mlp_W1  = (const float*)d_in[15];
    const float* mlp_b1  = (const float*)d_in[16];
    const float* mlp_W2  = (const float*)d_in[17];
    const float* mlp_b2  = (const float*)d_in[18];
    const float* lin1_W  = (const float*)d_in[19];
    const float* lin1_b  = (const float*)d_in[20];
    const float* lin2_W  = (const float*)d_in[21];
    const float* lin2_b  = (const float*)d_in[22];

    const long S = (long)B_ * N_ * HID;            // 3,145,728
    char* base = (char*)d_ws;
    float* h      = (float*)(base);
    float* tmp1   = (float*)(base + (size_t)S * 4);       // xw / attn-out(bf16) / u / pool-partial / nhh+nhl
    float* hlocal = (float*)(base + (size_t)S * 8);
    float* outb   = (float*)(base + (size_t)S * 12);
    char*  tzone  = base + (size_t)S * 16;                // 8S-byte multi-use region
    float* proj   = (float*)(base + (size_t)S * 24);
    float*  sim = (float*)tzone;                          // phase-1 (spills into proj)
    ushort* qkbf = (ushort*)tzone;                        // [0,4S): fused q|k rows stride 768
    ushort* vbT  = (ushort*)(tzone + (size_t)S * 4);      // [4S,6S)
    ushort* outb_bf = (ushort*)(tzone + (size_t)S * 6);   // [6S,8S)
    ushort* tb  = (ushort*)tzone;                         // [0,4S) after attn (mlp hidden)
    ushort* nhh = (ushort*)(base + (size_t)S * 4);        // phase-1 overlay of tmp1
    ushort* nhl = (ushort*)(base + (size_t)S * 6);
    int*    knn    = (int*)(base + (size_t)S * 28);
    float*  pooled = (float*)(base + (size_t)S * 28 + 524288);
    ushort* wts    = (ushort*)(base + (size_t)S * 28 + 524288 + 16384);
    const long SQ = (long)HID * HID;
    ushort* w1T = wts + 15 * SQ;
    ushort* w2T = w1T + 3 * (long)HID * 2 * HID;
    ushort* hb  = (ushort*)(base + (size_t)S * 28 + 524288 + 16384 + 7962624);
    float* gqkvb = (float*)(base + (size_t)S * 28 + 524288 + 16384 + 7962624 + (size_t)S * 2);
    float* partial = tmp1;
    ushort* obf = (ushort*)tmp1;                          // attn bf16 out (tmp1 dead)

    // ---- weight cast+transpose (bf16 [N][K]) + bias concat
    k_cast15<<<dim3(12, 12, 15), 256, 0, stream>>>(gcn_W, Wq, Wk, Wv, Wo, wts);
    k_castT<<<dim3(24, 12, 3), 256, 0, stream>>>(mlp_W1, w1T, HID, 2 * HID);
    k_castT<<<dim3(12, 24, 3), 256, 0, stream>>>(mlp_W2, w2T, 2 * HID, HID);
    k_biasgqkv<<<3, 384, 0, stream>>>(gcn_b, bq, bk, bv, gqkvb);

    // ---- encode(+normalize+mirrors) + sim (hi/lo MFMA) + topk
    k_encode<<<B_ * N_, 128, 0, stream>>>(x, W_enc, b_enc, h, hb, nhh, nhl);
    k_sim<<<dim3(8, 8, 8), 256, 0, stream>>>(nhh, nhl, sim);
    k_topk<<<B_ * N_ / 4, 256, 0, stream>>>(sim, knn);

    const int M = B_ * N_;   // 8192
    for (int l = 0; l < L_; ++l) {
        const ushort* gqkvW = wts + (long)(l * 4) * SQ;       // [gcn|q|k|v] rows [1536][384]
        const ushort* woT   = wts + (long)(12 + l) * SQ;
        const ushort* w1Tl = w1T + (long)l * HID * 2 * HID;
        const ushort* w2Tl = w2T + (long)l * HID * 2 * HID;
        const float* bol = bo + (long)l * HID;
        const float* b1l = mlp_b1 + (long)l * 2 * HID;
        const float* b2l = mlp_b2 + (long)l * HID;
        const float* ls0 = ln_s + (long)(l * 3 + 0) * HID; const float* lb0 = ln_b + (long)(l * 3 + 0) * HID;
        const float* ls1 = ln_s + (long)(l * 3 + 1) * HID; const float* lb1 = ln_b + (long)(l * 3 + 1) * HID;
        const float* ls2 = ln_s + (long)(l * 3 + 2) * HID; const float* lb2 = ln_b + (long)(l * 3 + 2) * HID;

        // fused xw|q|k|v: one GEMM, N=1536 (xw f32 -> tmp1; q/k bf16 rows 768; v transposed)
        k_mgemm<5, false><<<dim3(1536 / 128, M / 128), 256, 0, stream>>>(
            hb, gqkvW, gqkvb + l * 1536, nullptr, qkbf, vbT, tmp1, M, 1536, HID, (long)M);
        k_gcn_ln<<<B_ * N_, 128, 0, stream>>>(h, tmp1, knn, ls0, lb0, hlocal);
        // attention -> obf (bf16); XCD-swizzled 1D grid
        k_attn<<<(N_ / 16) * NHEADS * B_, 256, 0, stream>>>(qkbf, vbT, obf);
        // proj = o @ Wo + bo (f32)
        k_mgemm<0, false><<<dim3(HID / 128, M / 128), 256, 0, stream>>>(
            obf, woT, bol, nullptr, proj, nullptr, nullptr, M, HID, HID, 0);
        // out = hlocal + LN(h + proj) -> outb (+bf16 mirror)
        k_addln<<<B_ * N_, 128, 0, stream>>>(h, proj, hlocal, ls1, lb1, outb, outb_bf);
        // t = relu(out @ W1 + b1) -> bf16 tb
        k_mgemm<1, true><<<dim3(2 * HID / 128, M / 128), 256, 0, stream>>>(
            outb_bf, w1Tl, b1l, nullptr, tb, nullptr, nullptr, M, 2 * HID, HID, 0);
        // u = out + t @ W2 + b2 -> tmp1 (f32)
        k_mgemm<0, false><<<dim3(HID / 128, M / 128), 256, 0, stream>>>(
            tb, w2Tl, b2l, outb, tmp1, nullptr, nullptr, M, HID, 2 * HID, 0);
        // h = LN(u) (+hb mirror)
        k_addln<<<B_ * N_, 128, 0, stream>>>(tmp1, nullptr, nullptr, ls2, lb2, h, hb);
    }

    k_pool1<<<dim3(32, B_), 384, 0, stream>>>(h, partial);
    k_pool2<<<B_, 384, 0, stream>>>(partial, pooled);
    k_head<<<B_, HID, 0, stream>>>(pooled, lin1_W, lin1_b, lin2_W, lin2_b,
                                   (float*)d_out);
}